// Round 1
// baseline (670.083 us; speedup 1.0000x reference)
//
#include <hip/hip_runtime.h>
#include <math.h>

#define NNODES 50000
#define NEDGES 800000

__device__ __forceinline__ float lrelu(float x){ return x > 0.f ? x : 0.2f*x; }
__device__ __forceinline__ float elu_f(float x){ return x > 0.f ? x : expm1f(x); }

// ---------------- GEMM: C[N,Cc] = A[N,128] @ B[128,Cc], f32 vector ALU ----------------
__global__ __launch_bounds__(256)
void gemm128(const float* __restrict__ A, const float* __restrict__ B,
             float* __restrict__ C, int N, int Cc)
{
    __shared__ float As[64][68];   // As[k][m] (A transposed in LDS), pad to 68 for alignment
    __shared__ float Bs[64][68];   // Bs[k][n]
    const int bm = blockIdx.x * 64, bn = blockIdx.y * 64;
    const int tid = threadIdx.x;
    const int tr = (tid >> 4) << 2;   // 0..60, row offset of 4x4 micro-tile
    const int tc = (tid & 15) << 2;   // 0..60, col offset
    float acc[4][4] = {};

    for (int kt = 0; kt < 128; kt += 64) {
        // stage A tile (64 rows x 64 k), transposed
        for (int L = tid; L < 64*16; L += 256) {
            int r = L >> 4, k4 = (L & 15) << 2;
            int gr = bm + r;
            float4 v = make_float4(0.f,0.f,0.f,0.f);
            if (gr < N) v = *(const float4*)(A + (size_t)gr*128 + kt + k4);
            As[k4+0][r] = v.x; As[k4+1][r] = v.y; As[k4+2][r] = v.z; As[k4+3][r] = v.w;
        }
        // stage B tile (64 k x 64 cols), scalar loads (Cc may be 194 -> unaligned)
        for (int L = tid; L < 64*16; L += 256) {
            int k = L >> 4, c4 = (L & 15) << 2;
            int gc = bn + c4;
            const float* Brow = B + (size_t)(kt + k) * Cc;
            float4 v;
            v.x = (gc+0 < Cc) ? Brow[gc+0] : 0.f;
            v.y = (gc+1 < Cc) ? Brow[gc+1] : 0.f;
            v.z = (gc+2 < Cc) ? Brow[gc+2] : 0.f;
            v.w = (gc+3 < Cc) ? Brow[gc+3] : 0.f;
            *(float4*)&Bs[k][c4] = v;
        }
        __syncthreads();
        #pragma unroll 8
        for (int k = 0; k < 64; k++) {
            float4 a = *(const float4*)&As[k][tr];
            float4 b = *(const float4*)&Bs[k][tc];
            acc[0][0] += a.x*b.x; acc[0][1] += a.x*b.y; acc[0][2] += a.x*b.z; acc[0][3] += a.x*b.w;
            acc[1][0] += a.y*b.x; acc[1][1] += a.y*b.y; acc[1][2] += a.y*b.z; acc[1][3] += a.y*b.w;
            acc[2][0] += a.z*b.x; acc[2][1] += a.z*b.y; acc[2][2] += a.z*b.z; acc[2][3] += a.z*b.w;
            acc[3][0] += a.w*b.x; acc[3][1] += a.w*b.y; acc[3][2] += a.w*b.z; acc[3][3] += a.w*b.w;
        }
        __syncthreads();
    }
    for (int i = 0; i < 4; i++) {
        int gr = bm + tr + i;
        if (gr >= N) continue;
        for (int j = 0; j < 4; j++) {
            int gc = bn + tc + j;
            if (gc < Cc) C[(size_t)gr*Cc + gc] = acc[i][j];
        }
    }
}

// ---------------- el/er: el[n,h] = sum_d ft[n,h,d]*al[h,d] ----------------
template<int C, int D>
__global__ void compute_elr(const float* __restrict__ ft, const float* __restrict__ al,
                            const float* __restrict__ ar, float* __restrict__ el,
                            float* __restrict__ er, int N)
{
    int wv = threadIdx.x >> 6, lane = threadIdx.x & 63;
    int n = blockIdx.x * 4 + wv;
    if (n >= N) return;
    const float* row = ft + (size_t)n * C;
    float l0=0.f, l1=0.f, r0=0.f, r1=0.f;
    for (int c = lane; c < C; c += 64) {
        float v = row[c];
        float vl = v * al[c], vr = v * ar[c];
        if (c < D) { l0 += vl; r0 += vr; } else { l1 += vl; r1 += vr; }
    }
    #pragma unroll
    for (int off = 32; off; off >>= 1) {
        l0 += __shfl_down(l0, off); l1 += __shfl_down(l1, off);
        r0 += __shfl_down(r0, off); r1 += __shfl_down(r1, off);
    }
    if (lane == 0) { el[2*n] = l0; el[2*n+1] = l1; er[2*n] = r0; er[2*n+1] = r1; }
}

// ---------------- CSR build ----------------
__global__ void hist_kernel(const int* __restrict__ dst, int* __restrict__ counts, int E)
{
    int i = blockIdx.x * blockDim.x + threadIdx.x;
    if (i < E) atomicAdd(&counts[dst[i]], 1);
}

__global__ void scan_kernel(const int* __restrict__ counts, int* __restrict__ row_start, int n)
{
    __shared__ int buf[1024];
    __shared__ int carryS;
    const int tid = threadIdx.x;
    if (tid == 0) carryS = 0;
    __syncthreads();
    for (int base = 0; base < n; base += 1024) {
        int i = base + tid;
        int v = (i < n) ? counts[i] : 0;
        buf[tid] = v; __syncthreads();
        for (int off = 1; off < 1024; off <<= 1) {
            int t = (tid >= off) ? buf[tid - off] : 0;
            __syncthreads();
            buf[tid] += t;
            __syncthreads();
        }
        int cbase = carryS;
        if (i < n) row_start[i + 1] = cbase + buf[tid];
        __syncthreads();
        if (tid == 0) carryS += buf[1023];
        __syncthreads();
    }
    if (tid == 0) row_start[0] = 0;
}

__global__ void scatter_kernel(const int* __restrict__ src, const int* __restrict__ dst,
                               const int* __restrict__ row_start, int* __restrict__ cursor,
                               int* __restrict__ src_sorted, int E)
{
    int i = blockIdx.x * blockDim.x + threadIdx.x;
    if (i < E) {
        int d = dst[i];
        int p = atomicAdd(&cursor[d], 1);
        src_sorted[row_start[d] + p] = src[i];
    }
}

// ---------------- per-dst-node edge softmax + weighted aggregation ----------------
// MODE 0: no residual, ELU, write [N,C].  MODE 1: identity residual, ELU, write [N,C].
// MODE 2: residual buffer, no act, mean over heads, write [N-1, D].
template<int C, int D, int MODE>
__global__ __launch_bounds__(128)
void gat_agg(const float* __restrict__ ft, const float* __restrict__ el,
             const float* __restrict__ er, const int* __restrict__ row_start,
             const int* __restrict__ src_sorted, const float* __restrict__ res,
             const float* __restrict__ bias, float* __restrict__ out, int N)
{
    __shared__ int   s_src[64];
    __shared__ float s_w[2][64];
    __shared__ float s_m[2];
    __shared__ float s_den[2];
    const int n = blockIdx.x;
    const int tid = threadIdx.x;
    const int beg = row_start[n];
    const int deg = row_start[n + 1] - beg;
    const float ern0 = er[2*n], ern1 = er[2*n+1];
    float acc0 = 0.f, acc1 = 0.f;

    if (deg > 0) {
        // pass 1: per-head max of edge logits (wave 0)
        if (tid < 64) {
            float m0 = -INFINITY, m1 = -INFINITY;
            for (int i = tid; i < deg; i += 64) {
                int s = src_sorted[beg + i];
                m0 = fmaxf(m0, lrelu(el[2*s]   + ern0));
                m1 = fmaxf(m1, lrelu(el[2*s+1] + ern1));
            }
            #pragma unroll
            for (int off = 32; off; off >>= 1) {
                m0 = fmaxf(m0, __shfl_down(m0, off));
                m1 = fmaxf(m1, __shfl_down(m1, off));
            }
            if (tid == 0) { s_m[0] = m0; s_m[1] = m1; s_den[0] = 0.f; s_den[1] = 0.f; }
        }
        __syncthreads();
        const float m0 = s_m[0], m1 = s_m[1];

        // pass 2: chunked exp-weights + accumulation
        for (int cb = 0; cb < deg; cb += 64) {
            const int cnt = min(64, deg - cb);
            if (tid < 64) {
                float w0 = 0.f, w1 = 0.f; int s = 0;
                if (tid < cnt) {
                    s = src_sorted[beg + cb + tid];
                    w0 = __expf(lrelu(el[2*s]   + ern0) - m0);
                    w1 = __expf(lrelu(el[2*s+1] + ern1) - m1);
                }
                s_src[tid] = s; s_w[0][tid] = w0; s_w[1][tid] = w1;
                float d0 = w0, d1 = w1;
                #pragma unroll
                for (int off = 32; off; off >>= 1) {
                    d0 += __shfl_down(d0, off);
                    d1 += __shfl_down(d1, off);
                }
                if (tid == 0) { s_den[0] += d0; s_den[1] += d1; }
            }
            __syncthreads();
            if constexpr (MODE < 2) {
                if (tid < C) {
                    const int h = tid / D;
                    for (int t = 0; t < cnt; t++)
                        acc0 += s_w[h][t] * ft[(size_t)s_src[t]*C + tid];
                }
            } else {
                if (tid < D) {
                    for (int t = 0; t < cnt; t++) {
                        const float* fr = ft + (size_t)s_src[t]*C;
                        acc0 += s_w[0][t] * fr[tid];
                        acc1 += s_w[1][t] * fr[D + tid];
                    }
                }
            }
            __syncthreads();
        }
    }

    if constexpr (MODE < 2) {
        if (tid < C) {
            const int h = tid / D;
            float rst = (deg > 0) ? acc0 / s_den[h] : 0.f;
            float v = rst + bias[tid];
            if constexpr (MODE == 1) v += res[(size_t)n*C + tid];
            out[(size_t)n*C + tid] = elu_f(v);
        }
    } else {
        if (tid < D && n < N - 1) {
            float r0 = (deg > 0) ? acc0 / s_den[0] : 0.f;
            float r1 = (deg > 0) ? acc1 / s_den[1] : 0.f;
            float v0 = r0 + res[(size_t)n*C + tid]     + bias[tid];
            float v1 = r1 + res[(size_t)n*C + D + tid] + bias[D + tid];
            out[(size_t)n*(size_t)D + tid] = 0.5f * (v0 + v1);
        }
    }
}

extern "C" void kernel_launch(void* const* d_in, const int* in_sizes, int n_in,
                              void* d_out, int out_size, void* d_ws, size_t ws_size,
                              hipStream_t stream)
{
    const float* x   = (const float*)d_in[0];
    const int*   esrc= (const int*)  d_in[1];
    const int*   edst= (const int*)  d_in[2];
    const float* W0  = (const float*)d_in[3];
    const float* al0 = (const float*)d_in[4];
    const float* ar0 = (const float*)d_in[5];
    const float* b0  = (const float*)d_in[6];
    const float* W1  = (const float*)d_in[7];
    const float* al1 = (const float*)d_in[8];
    const float* ar1 = (const float*)d_in[9];
    const float* b1  = (const float*)d_in[10];
    const float* W2  = (const float*)d_in[11];
    const float* al2 = (const float*)d_in[12];
    const float* ar2 = (const float*)d_in[13];
    const float* b2  = (const float*)d_in[14];
    const float* rW2 = (const float*)d_in[15];
    float* out = (float*)d_out;

    const int N = NNODES, E = NEDGES;
    float* ws = (float*)d_ws;
    size_t o = 0;
    float* h1  = ws + o; o += (size_t)N * 128;
    float* h2  = ws + o; o += (size_t)N * 128;
    float* ft  = ws + o; o += (size_t)N * 194;
    float* rs2 = ws + o; o += (size_t)N * 194;
    float* el  = ws + o; o += (size_t)N * 2;
    float* er  = ws + o; o += (size_t)N * 2;
    int* row_start = (int*)(ws + o); o += N + 1;
    int* cursor    = (int*)(ws + o); o += N;
    int* ssorted   = (int*)(ws + o); o += E;

    // CSR by dst (recomputed every call; deterministic)
    hipMemsetAsync(cursor, 0, N * sizeof(int), stream);
    hist_kernel<<<(E + 255) / 256, 256, 0, stream>>>(edst, cursor, E);
    scan_kernel<<<1, 1024, 0, stream>>>(cursor, row_start, N);
    hipMemsetAsync(cursor, 0, N * sizeof(int), stream);
    scatter_kernel<<<(E + 255) / 256, 256, 0, stream>>>(esrc, edst, row_start, cursor, ssorted, E);

    dim3 g128((N + 63) / 64, 2), g194((N + 63) / 64, 4);
    int elr_grid = (N + 3) / 4;

    // layer 0: no residual, ELU
    gemm128<<<g128, 256, 0, stream>>>(x, W0, ft, N, 128);
    compute_elr<128,64><<<elr_grid, 256, 0, stream>>>(ft, al0, ar0, el, er, N);
    gat_agg<128,64,0><<<N, 128, 0, stream>>>(ft, el, er, row_start, ssorted, nullptr, b0, h1, N);

    // layer 1: identity residual, ELU
    gemm128<<<g128, 256, 0, stream>>>(h1, W1, ft, N, 128);
    compute_elr<128,64><<<elr_grid, 256, 0, stream>>>(ft, al1, ar1, el, er, N);
    gat_agg<128,64,1><<<N, 128, 0, stream>>>(ft, el, er, row_start, ssorted, h1, b1, h2, N);

    // layer 2: linear residual, no act, mean heads, drop last node
    gemm128<<<g194, 256, 0, stream>>>(h2, W2, ft, N, 194);
    gemm128<<<g194, 256, 0, stream>>>(h2, rW2, rs2, N, 194);
    compute_elr<194,97><<<elr_grid, 256, 0, stream>>>(ft, al2, ar2, el, er, N);
    gat_agg<194,97,2><<<N, 128, 0, stream>>>(ft, el, er, row_start, ssorted, rs2, b2, out, N);
}

// Round 2
// 457.222 us; speedup vs baseline: 1.4656x; 1.4656x over previous
//
#include <hip/hip_runtime.h>
#include <math.h>

#define NNODES 50000
#define NEDGES 800000

typedef unsigned int uint;
typedef unsigned short ushort_t;
typedef __bf16 bf16x8 __attribute__((ext_vector_type(8)));
typedef float f32x4 __attribute__((ext_vector_type(4)));

__device__ __forceinline__ float lrelu(float x){ return x > 0.f ? x : 0.2f*x; }
__device__ __forceinline__ float elu_f(float x){ return x > 0.f ? x : expm1f(x); }
__device__ __forceinline__ unsigned short f2bf(float f){
    uint u = __float_as_uint(f);
    return (unsigned short)((u + 0x7fffu + ((u >> 16) & 1u)) >> 16);
}
__device__ __forceinline__ float bf2f(unsigned short h){ return __uint_as_float(((uint)h) << 16); }

// ============ GEMM: C[N,Cc] = A[N,128] @ B[128,Cc] via bf16x3-split MFMA ============
// Block tile 128x64, 4 waves (2 row x 2 col), wave tile 64x32, K-step 32.
template<bool OUTBF>
__global__ __launch_bounds__(256)
void gemm_mfma(const float* __restrict__ A, const float* __restrict__ B,
               void* __restrict__ Cout, int N, int Cc)
{
    __shared__ unsigned short Ah[128*40];
    __shared__ unsigned short Al[128*40];
    __shared__ unsigned short Bh[64*40];
    __shared__ unsigned short Bl[64*40];
    const int bm = blockIdx.x * 128, bn = blockIdx.y * 64;
    const int tid = threadIdx.x;
    const int wid = tid >> 6, lane = tid & 63;
    const int lr = lane & 15;                 // fragment row/col index
    const int lk = (lane >> 4) << 3;          // k offset within 32: 0,8,16,24
    const int wrow = (wid & 1) * 64, wcol = (wid >> 1) * 32;
    f32x4 acc[4][2] = {};

    for (int kt = 0; kt < 128; kt += 32) {
        // stage A tile: 128 rows x 32 k, split hi/lo bf16
        for (int L = tid; L < 128*8; L += 256) {
            int r = L >> 3, k4 = (L & 7) << 2;
            int gr = bm + r;
            float4 v = make_float4(0.f,0.f,0.f,0.f);
            if (gr < N) v = *(const float4*)(A + (size_t)gr*128 + kt + k4);
            float fv[4] = {v.x, v.y, v.z, v.w};
            unsigned short hs[4], ls[4];
            #pragma unroll
            for (int j = 0; j < 4; j++) {
                hs[j] = f2bf(fv[j]);
                ls[j] = f2bf(fv[j] - bf2f(hs[j]));
            }
            *(ushort4*)&Ah[r*40 + k4] = make_ushort4(hs[0],hs[1],hs[2],hs[3]);
            *(ushort4*)&Al[r*40 + k4] = make_ushort4(ls[0],ls[1],ls[2],ls[3]);
        }
        // stage B tile transposed: [col][k], 32 k x 64 cols
        for (int L = tid; L < 2048; L += 256) {
            int k = L >> 6, c = L & 63;
            int gc = bn + c;
            float v = (gc < Cc) ? B[(size_t)(kt + k)*Cc + gc] : 0.f;
            unsigned short h = f2bf(v);
            unsigned short l = f2bf(v - bf2f(h));
            Bh[c*40 + k] = h;
            Bl[c*40 + k] = l;
        }
        __syncthreads();
        bf16x8 aH[4], aL[4], bH[2], bL[2];
        #pragma unroll
        for (int fr = 0; fr < 4; fr++) {
            int off = (wrow + fr*16 + lr)*40 + lk;
            aH[fr] = *(const bf16x8*)&Ah[off];
            aL[fr] = *(const bf16x8*)&Al[off];
        }
        #pragma unroll
        for (int fs = 0; fs < 2; fs++) {
            int off = (wcol + fs*16 + lr)*40 + lk;
            bH[fs] = *(const bf16x8*)&Bh[off];
            bL[fs] = *(const bf16x8*)&Bl[off];
        }
        #pragma unroll
        for (int fr = 0; fr < 4; fr++)
            #pragma unroll
            for (int fs = 0; fs < 2; fs++) {
                acc[fr][fs] = __builtin_amdgcn_mfma_f32_16x16x32_bf16(aH[fr], bH[fs], acc[fr][fs], 0, 0, 0);
                acc[fr][fs] = __builtin_amdgcn_mfma_f32_16x16x32_bf16(aH[fr], bL[fs], acc[fr][fs], 0, 0, 0);
                acc[fr][fs] = __builtin_amdgcn_mfma_f32_16x16x32_bf16(aL[fr], bH[fs], acc[fr][fs], 0, 0, 0);
            }
        __syncthreads();
    }
    // epilogue: D lane mapping: row = 4*(lane>>4)+v, col = lane&15
    #pragma unroll
    for (int fr = 0; fr < 4; fr++)
        #pragma unroll
        for (int fs = 0; fs < 2; fs++)
            #pragma unroll
            for (int v = 0; v < 4; v++) {
                int row = bm + wrow + fr*16 + ((lane >> 4) << 2) + v;
                int col = bn + wcol + fs*16 + lr;
                if (row < N && col < Cc) {
                    if (OUTBF) ((unsigned short*)Cout)[(size_t)row*Cc + col] = f2bf(acc[fr][fs][v]);
                    else       ((float*)Cout)[(size_t)row*Cc + col] = acc[fr][fs][v];
                }
            }
}

// ============ el/er from bf16 ft ============
template<int C, int D>
__global__ void compute_elr(const uint* __restrict__ ftb, const float* __restrict__ al,
                            const float* __restrict__ ar, float* __restrict__ el,
                            float* __restrict__ er, int N)
{
    int wv = threadIdx.x >> 6, lane = threadIdx.x & 63;
    int n = blockIdx.x * 4 + wv;
    if (n >= N) return;
    const uint* row = ftb + (size_t)n * (C/2);
    float l0=0.f, l1=0.f, r0=0.f, r1=0.f;
    for (int p = lane; p < C/2; p += 64) {
        uint u = row[p];
        float f0 = __uint_as_float(u << 16);
        float f1 = __uint_as_float(u & 0xffff0000u);
        int c0 = 2*p, c1 = 2*p + 1;
        float a0 = al[c0], a1 = al[c1], g0 = ar[c0], g1 = ar[c1];
        if (c0 < D) { l0 += f0*a0; r0 += f0*g0; } else { l1 += f0*a0; r1 += f0*g0; }
        if (c1 < D) { l0 += f1*a1; r0 += f1*g1; } else { l1 += f1*a1; r1 += f1*g1; }
    }
    #pragma unroll
    for (int off = 32; off; off >>= 1) {
        l0 += __shfl_down(l0, off); l1 += __shfl_down(l1, off);
        r0 += __shfl_down(r0, off); r1 += __shfl_down(r1, off);
    }
    if (lane == 0) { el[2*n] = l0; el[2*n+1] = l1; er[2*n] = r0; er[2*n+1] = r1; }
}

// ============ CSR build ============
__global__ void hist_kernel(const int* __restrict__ dst, int* __restrict__ counts, int E)
{
    int i = blockIdx.x * blockDim.x + threadIdx.x;
    if (i < E) atomicAdd(&counts[dst[i]], 1);
}

__global__ __launch_bounds__(1024)
void scan_kernel(const int* __restrict__ counts, int* __restrict__ row_start, int n)
{
    __shared__ int wsum[16];
    __shared__ int s_carry;
    const int tid = threadIdx.x, lane = tid & 63, wv = tid >> 6;
    if (tid == 0) { s_carry = 0; row_start[0] = 0; }
    __syncthreads();
    for (int base = 0; base < n; base += 4096) {
        int i0 = base + tid*4;
        int v[4];
        #pragma unroll
        for (int j = 0; j < 4; j++) { int i = i0 + j; v[j] = (i < n) ? counts[i] : 0; }
        v[1] += v[0]; v[2] += v[1]; v[3] += v[2];
        int t = v[3];
        #pragma unroll
        for (int off = 1; off < 64; off <<= 1) {
            int u = __shfl_up(t, off);
            if (lane >= off) t += u;
        }
        int wtot = __shfl(t, 63);
        int texcl = t - v[3];
        if (lane == 63) wsum[wv] = wtot;
        __syncthreads();
        int woff = 0;
        for (int w = 0; w < 16; w++) if (w < wv) woff += wsum[w];
        int basev = s_carry + woff + texcl;
        #pragma unroll
        for (int j = 0; j < 4; j++) { int i = i0 + j; if (i < n) row_start[i+1] = basev + v[j]; }
        __syncthreads();
        if (tid == 0) {
            int tot = 0;
            for (int w = 0; w < 16; w++) tot += wsum[w];
            s_carry += tot;
        }
        __syncthreads();
    }
}

__global__ void scatter_kernel(const int* __restrict__ src, const int* __restrict__ dst,
                               const int* __restrict__ row_start, int* __restrict__ cursor,
                               int* __restrict__ src_sorted, int E)
{
    int i = blockIdx.x * blockDim.x + threadIdx.x;
    if (i < E) {
        int d = dst[i];
        int p = atomicAdd(&cursor[d], 1);
        src_sorted[row_start[d] + p] = src[i];
    }
}

// ============ aggregation, C=128 D=64 layers (MODE 0: no res; MODE 1: identity res) ============
template<int MODE>
__global__ __launch_bounds__(64)
void gat_agg128(const uint* __restrict__ ftb, const float* __restrict__ el,
                const float* __restrict__ er, const int* __restrict__ row_start,
                const int* __restrict__ src_sorted, const float* __restrict__ res,
                const float* __restrict__ bias, float* __restrict__ out, int N)
{
    __shared__ int   s_src[64];
    __shared__ float s_w[2][64];
    __shared__ float s_m[2];
    __shared__ float s_den[2];
    const int n = blockIdx.x, d = threadIdx.x;
    const int beg = row_start[n];
    const int deg = row_start[n+1] - beg;
    const float2 ern = *(const float2*)(er + 2*(size_t)n);
    const int h = d >> 5;   // cols 2d,2d+1: head = (2d)/64
    float ax = 0.f, ay = 0.f;

    if (deg > 0) {
        float m0 = -INFINITY, m1 = -INFINITY;
        for (int i = d; i < deg; i += 64) {
            int s = src_sorted[beg + i];
            float2 e = *(const float2*)(el + 2*(size_t)s);
            m0 = fmaxf(m0, lrelu(e.x + ern.x));
            m1 = fmaxf(m1, lrelu(e.y + ern.y));
        }
        #pragma unroll
        for (int off = 32; off; off >>= 1) {
            m0 = fmaxf(m0, __shfl_down(m0, off));
            m1 = fmaxf(m1, __shfl_down(m1, off));
        }
        if (d == 0) { s_m[0] = m0; s_m[1] = m1; s_den[0] = 0.f; s_den[1] = 0.f; }
        __syncthreads();
        m0 = s_m[0]; m1 = s_m[1];

        for (int cb = 0; cb < deg; cb += 64) {
            const int cnt = min(64, deg - cb);
            float w0 = 0.f, w1 = 0.f; int s = 0;
            if (d < cnt) {
                s = src_sorted[beg + cb + d];
                float2 e = *(const float2*)(el + 2*(size_t)s);
                w0 = __expf(lrelu(e.x + ern.x) - m0);
                w1 = __expf(lrelu(e.y + ern.y) - m1);
            }
            s_src[d] = s; s_w[0][d] = w0; s_w[1][d] = w1;
            float d0 = w0, d1 = w1;
            #pragma unroll
            for (int off = 32; off; off >>= 1) {
                d0 += __shfl_down(d0, off);
                d1 += __shfl_down(d1, off);
            }
            if (d == 0) { s_den[0] += d0; s_den[1] += d1; }
            __syncthreads();
            for (int t = 0; t < cnt; t++) {
                int sv = s_src[t];
                float w = s_w[h][t];
                uint u = ftb[(size_t)sv*64 + d];
                ax += w * __uint_as_float(u << 16);
                ay += w * __uint_as_float(u & 0xffff0000u);
            }
            __syncthreads();
        }
    }
    float den = s_den[h];
    float r0 = (deg > 0) ? ax / den : 0.f;
    float r1 = (deg > 0) ? ay / den : 0.f;
    const int c0 = 2*d;
    float2 bv = *(const float2*)(bias + c0);
    float v0 = r0 + bv.x, v1 = r1 + bv.y;
    if (MODE == 1) {
        float2 rv = *(const float2*)(res + (size_t)n*128 + c0);
        v0 += rv.x; v1 += rv.y;
    }
    float2 o; o.x = elu_f(v0); o.y = elu_f(v1);
    *(float2*)(out + (size_t)n*128 + c0) = o;
}

// ============ output-layer aggregation: C=194, D=97, res buffer, mean heads ============
__global__ __launch_bounds__(128)
void gat_agg_out(const uint* __restrict__ ftb, const float* __restrict__ el,
                 const float* __restrict__ er, const int* __restrict__ row_start,
                 const int* __restrict__ src_sorted, const float* __restrict__ res,
                 const float* __restrict__ bias, float* __restrict__ out, int N)
{
    __shared__ int   s_src[64];
    __shared__ float s_w[2][64];
    __shared__ float s_m[2];
    __shared__ float s_den[2];
    __shared__ float s_acc[194];
    const int n = blockIdx.x, tid = threadIdx.x;
    const int beg = row_start[n];
    const int deg = row_start[n+1] - beg;
    const float2 ern = *(const float2*)(er + 2*(size_t)n);
    const int c0 = 2*tid, c1 = 2*tid + 1;  // valid when tid<97
    float ax = 0.f, ay = 0.f;

    if (deg > 0) {
        if (tid < 64) {
            float m0 = -INFINITY, m1 = -INFINITY;
            for (int i = tid; i < deg; i += 64) {
                int s = src_sorted[beg + i];
                float2 e = *(const float2*)(el + 2*(size_t)s);
                m0 = fmaxf(m0, lrelu(e.x + ern.x));
                m1 = fmaxf(m1, lrelu(e.y + ern.y));
            }
            #pragma unroll
            for (int off = 32; off; off >>= 1) {
                m0 = fmaxf(m0, __shfl_down(m0, off));
                m1 = fmaxf(m1, __shfl_down(m1, off));
            }
            if (tid == 0) { s_m[0] = m0; s_m[1] = m1; s_den[0] = 0.f; s_den[1] = 0.f; }
        }
        __syncthreads();
        const float m0 = s_m[0], m1 = s_m[1];

        for (int cb = 0; cb < deg; cb += 64) {
            const int cnt = min(64, deg - cb);
            if (tid < 64) {
                float w0 = 0.f, w1 = 0.f; int s = 0;
                if (tid < cnt) {
                    s = src_sorted[beg + cb + tid];
                    float2 e = *(const float2*)(el + 2*(size_t)s);
                    w0 = __expf(lrelu(e.x + ern.x) - m0);
                    w1 = __expf(lrelu(e.y + ern.y) - m1);
                }
                s_src[tid] = s; s_w[0][tid] = w0; s_w[1][tid] = w1;
                float d0 = w0, d1 = w1;
                #pragma unroll
                for (int off = 32; off; off >>= 1) {
                    d0 += __shfl_down(d0, off);
                    d1 += __shfl_down(d1, off);
                }
                if (tid == 0) { s_den[0] += d0; s_den[1] += d1; }
            }
            __syncthreads();
            if (tid < 97) {
                const bool h0lo = (c0 < 97), h1lo = (c1 < 97);
                for (int t = 0; t < cnt; t++) {
                    int sv = s_src[t];
                    float w0 = s_w[0][t], w1 = s_w[1][t];
                    uint u = ftb[(size_t)sv*97 + tid];
                    ax += (h0lo ? w0 : w1) * __uint_as_float(u << 16);
                    ay += (h1lo ? w0 : w1) * __uint_as_float(u & 0xffff0000u);
                }
            }
            __syncthreads();
        }
    }
    if (tid < 97) {
        float dx = s_den[(c0 < 97) ? 0 : 1];
        float dy = s_den[(c1 < 97) ? 0 : 1];
        s_acc[c0] = (deg > 0) ? ax / dx : 0.f;
        s_acc[c1] = (deg > 0) ? ay / dy : 0.f;
    }
    __syncthreads();
    if (tid < 97 && n < N - 1) {
        float v0 = s_acc[tid]      + res[(size_t)n*194 + tid]      + bias[tid];
        float v1 = s_acc[97 + tid] + res[(size_t)n*194 + 97 + tid] + bias[97 + tid];
        out[(size_t)n*97 + tid] = 0.5f * (v0 + v1);
    }
}

extern "C" void kernel_launch(void* const* d_in, const int* in_sizes, int n_in,
                              void* d_out, int out_size, void* d_ws, size_t ws_size,
                              hipStream_t stream)
{
    const float* x   = (const float*)d_in[0];
    const int*   esrc= (const int*)  d_in[1];
    const int*   edst= (const int*)  d_in[2];
    const float* W0  = (const float*)d_in[3];
    const float* al0 = (const float*)d_in[4];
    const float* ar0 = (const float*)d_in[5];
    const float* b0  = (const float*)d_in[6];
    const float* W1  = (const float*)d_in[7];
    const float* al1 = (const float*)d_in[8];
    const float* ar1 = (const float*)d_in[9];
    const float* b1  = (const float*)d_in[10];
    const float* W2  = (const float*)d_in[11];
    const float* al2 = (const float*)d_in[12];
    const float* ar2 = (const float*)d_in[13];
    const float* b2  = (const float*)d_in[14];
    const float* rW2 = (const float*)d_in[15];
    float* out = (float*)d_out;

    const int N = NNODES, E = NEDGES;
    float* ws = (float*)d_ws;
    size_t o = 0;
    float* h1  = ws + o; o += (size_t)N * 128;
    float* h2  = ws + o; o += (size_t)N * 128;
    float* rs2 = ws + o; o += (size_t)N * 194;
    float* el  = ws + o; o += (size_t)N * 2;
    float* er  = ws + o; o += (size_t)N * 2;
    uint* ftb  = (uint*)(ws + o); o += (size_t)N * 97;   // bf16 ft, max 194 cols = 97 u32/row
    int* row_start = (int*)(ws + o); o += N + 1;
    int* cursor    = (int*)(ws + o); o += N;
    int* ssorted   = (int*)(ws + o); o += E;

    // CSR by dst
    hipMemsetAsync(cursor, 0, N * sizeof(int), stream);
    hist_kernel<<<(E + 255) / 256, 256, 0, stream>>>(edst, cursor, E);
    scan_kernel<<<1, 1024, 0, stream>>>(cursor, row_start, N);
    hipMemsetAsync(cursor, 0, N * sizeof(int), stream);
    scatter_kernel<<<(E + 255) / 256, 256, 0, stream>>>(esrc, edst, row_start, cursor, ssorted, E);

    const int gm = (N + 127) / 128;           // 391
    dim3 g128(gm, 2), g194(gm, 4);
    int elr_grid = (N + 3) / 4;

    // layer 0
    gemm_mfma<true><<<g128, 256, 0, stream>>>(x, W0, ftb, N, 128);
    compute_elr<128,64><<<elr_grid, 256, 0, stream>>>(ftb, al0, ar0, el, er, N);
    gat_agg128<0><<<N, 64, 0, stream>>>(ftb, el, er, row_start, ssorted, nullptr, b0, h1, N);

    // layer 1 (identity residual)
    gemm_mfma<true><<<g128, 256, 0, stream>>>(h1, W1, ftb, N, 128);
    compute_elr<128,64><<<elr_grid, 256, 0, stream>>>(ftb, al1, ar1, el, er, N);
    gat_agg128<1><<<N, 64, 0, stream>>>(ftb, el, er, row_start, ssorted, h1, b1, h2, N);

    // output layer
    gemm_mfma<true ><<<g194, 256, 0, stream>>>(h2, W2,  ftb, N, 194);
    gemm_mfma<false><<<g194, 256, 0, stream>>>(h2, rW2, rs2, N, 194);
    compute_elr<194,97><<<elr_grid, 256, 0, stream>>>(ftb, al2, ar2, el, er, N);
    gat_agg_out<<<N - 1, 128, 0, stream>>>(ftb, el, er, row_start, ssorted, rs2, b2, out, N);
}